// Round 4
// baseline (381.102 us; speedup 1.0000x reference)
//
#include <hip/hip_runtime.h>
#include <cstdint>

#define HB 8
#define CM 128
#define NHEAD 8
#define NPT 8
#define DHD 16
#define HS 64
#define WS 64
#define LTOT 4096

typedef float floatx4 __attribute__((ext_vector_type(4)));
typedef short bf16x8 __attribute__((ext_vector_type(8)));

__device__ __forceinline__ unsigned short f2bf(float x) {
  unsigned u = __float_as_uint(x);
  return (unsigned short)((u + 0x7FFFu + ((u >> 16) & 1)) >> 16);
}
__device__ __forceinline__ float bf2f(unsigned short h) {
  return __uint_as_float(((unsigned)h) << 16);
}
__device__ __forceinline__ float fast_tanh(float x) {
  float e = __expf(2.0f * x);
  return 1.0f - 2.0f / (e + 1.0f);
}

// MFMA GEMM: C[l][n] = sum_k A[..] * W[k][n] + bias[n], K=CM=128.
// Block: 256 thr (4 waves), tile 64 l x 64 n. 3-term bf16 split (hi/lo).
// LDS swizzle: element (x,k) stored at x*128 + ((k>>3)^(x&15))*8 + (k&7)  [bf16 units]
// AMODE 0: A is [b][128][LTOT]  (k-major, lanes coalesce along l)
// AMODE 1: A is [b][LTOT][128]  (row-major)
// OUT 0: value layout out[((b*8 + c/16)*LTOT + l)*16 + c%16]
// OUT 1: row-major    out[(b*LTOT + l)*N + c]
// OUT 2: bchw         out[(b*CM + c)*LTOT + l]  (via LDS transpose epilogue)
template <int N, int AMODE, int OUT_MODE>
__global__ __launch_bounds__(256) void gemm_mfma(const float* __restrict__ A,
                                                 const float* __restrict__ W,
                                                 const float* __restrict__ bias,
                                                 float* __restrict__ out) {
  __shared__ char smem[65536];
  unsigned short* AB = (unsigned short*)smem;            // [2][64][128] bf16
  unsigned short* WB = (unsigned short*)(smem + 32768);  // [2][64][128] bf16
  const int t = threadIdx.x;
  const int ml0 = blockIdx.x * 64;
  const int nb0 = blockIdx.y * 64;
  const int b = blockIdx.z;

  // ---- stage A ----
  if (AMODE == 0) {
    const float* src = A + (size_t)b * CM * LTOT + ml0;
    const int x = t & 63, kq = t >> 6;
#pragma unroll
    for (int i = 0; i < 8; i++) {
      const int kb = kq * 4 + i * 16;
      const float v0 = src[(size_t)(kb + 0) * LTOT + x];
      const float v1 = src[(size_t)(kb + 1) * LTOT + x];
      const float v2 = src[(size_t)(kb + 2) * LTOT + x];
      const float v3 = src[(size_t)(kb + 3) * LTOT + x];
      ushort4 hi = {f2bf(v0), f2bf(v1), f2bf(v2), f2bf(v3)};
      ushort4 lo = {f2bf(v0 - bf2f(hi.x)), f2bf(v1 - bf2f(hi.y)),
                    f2bf(v2 - bf2f(hi.z)), f2bf(v3 - bf2f(hi.w))};
      const int off = x * 128 + (((kb >> 3) ^ (x & 15)) << 3) + (kb & 7);
      *(ushort4*)(AB + off) = hi;
      *(ushort4*)(AB + 8192 + off) = lo;
    }
  } else {
    const float* src = A + ((size_t)b * LTOT + ml0) * CM;
#pragma unroll
    for (int i = 0; i < 8; i++) {
      const int idx = t + i * 256;
      const int x = idx >> 5;          // row l (0..63)
      const int kb = (idx & 31) * 4;   // k base
      const float4 v = *(const float4*)(src + (size_t)x * CM + kb);
      ushort4 hi = {f2bf(v.x), f2bf(v.y), f2bf(v.z), f2bf(v.w)};
      ushort4 lo = {f2bf(v.x - bf2f(hi.x)), f2bf(v.y - bf2f(hi.y)),
                    f2bf(v.z - bf2f(hi.z)), f2bf(v.w - bf2f(hi.w))};
      const int off = x * 128 + (((kb >> 3) ^ (x & 15)) << 3) + (kb & 7);
      *(ushort4*)(AB + off) = hi;
      *(ushort4*)(AB + 8192 + off) = lo;
    }
  }
  // ---- stage W (source [k][N], take cols nb0..nb0+63) ----
  {
    const float* src = W + nb0;
    const int x = t & 63, kq = t >> 6;
#pragma unroll
    for (int i = 0; i < 8; i++) {
      const int kb = kq * 4 + i * 16;
      const float v0 = src[(size_t)(kb + 0) * N + x];
      const float v1 = src[(size_t)(kb + 1) * N + x];
      const float v2 = src[(size_t)(kb + 2) * N + x];
      const float v3 = src[(size_t)(kb + 3) * N + x];
      ushort4 hi = {f2bf(v0), f2bf(v1), f2bf(v2), f2bf(v3)};
      ushort4 lo = {f2bf(v0 - bf2f(hi.x)), f2bf(v1 - bf2f(hi.y)),
                    f2bf(v2 - bf2f(hi.z)), f2bf(v3 - bf2f(hi.w))};
      const int off = x * 128 + (((kb >> 3) ^ (x & 15)) << 3) + (kb & 7);
      *(ushort4*)(WB + off) = hi;
      *(ushort4*)(WB + 8192 + off) = lo;
    }
  }
  __syncthreads();

  // ---- K loop ----
  const int w = t >> 6, lane = t & 63;
  const int wm = (w >> 1) * 32, wn = (w & 1) * 32;
  const int nl = lane & 15, q = lane >> 4;
  floatx4 acc[2][2];
#pragma unroll
  for (int mt = 0; mt < 2; mt++)
#pragma unroll
    for (int nt = 0; nt < 2; nt++) acc[mt][nt] = {0.0f, 0.0f, 0.0f, 0.0f};

#pragma unroll
  for (int K0 = 0; K0 < 4; K0++) {
    bf16x8 ah[2], al[2], bh[2], bl[2];
#pragma unroll
    for (int mt = 0; mt < 2; mt++) {
      const int m = wm + mt * 16 + nl;
      const int off = m * 128 + ((((K0 * 4 + q)) ^ (m & 15)) << 3);
      ah[mt] = *(bf16x8*)(AB + off);
      al[mt] = *(bf16x8*)(AB + 8192 + off);
    }
#pragma unroll
    for (int nt = 0; nt < 2; nt++) {
      const int n = wn + nt * 16 + nl;
      const int off = n * 128 + ((((K0 * 4 + q)) ^ (n & 15)) << 3);
      bh[nt] = *(bf16x8*)(WB + off);
      bl[nt] = *(bf16x8*)(WB + 8192 + off);
    }
#pragma unroll
    for (int mt = 0; mt < 2; mt++)
#pragma unroll
      for (int nt = 0; nt < 2; nt++) {
        acc[mt][nt] = __builtin_amdgcn_mfma_f32_16x16x32_bf16(al[mt], bh[nt], acc[mt][nt], 0, 0, 0);
        acc[mt][nt] = __builtin_amdgcn_mfma_f32_16x16x32_bf16(ah[mt], bl[nt], acc[mt][nt], 0, 0, 0);
        acc[mt][nt] = __builtin_amdgcn_mfma_f32_16x16x32_bf16(ah[mt], bh[nt], acc[mt][nt], 0, 0, 0);
      }
  }

  // ---- epilogue ----
  if (OUT_MODE == 2) {
    __syncthreads();  // done reading AB/WB; reuse as fp32 transpose buffer
    float* LF = (float*)smem;  // [64 n][65]
#pragma unroll
    for (int mt = 0; mt < 2; mt++)
#pragma unroll
      for (int nt = 0; nt < 2; nt++) {
        const int n = wn + nt * 16 + nl;
#pragma unroll
        for (int r = 0; r < 4; r++) {
          const int m = wm + mt * 16 + q * 4 + r;
          LF[n * 65 + m] = acc[mt][nt][r];
        }
      }
    __syncthreads();
#pragma unroll
    for (int i = 0; i < 16; i++) {
      const int idx = t + i * 256;
      const int n = idx >> 6, m = idx & 63;
      const int gc = nb0 + n;
      out[((size_t)b * CM + gc) * LTOT + ml0 + m] = LF[n * 65 + m] + bias[gc];
    }
  } else {
#pragma unroll
    for (int nt = 0; nt < 2; nt++) {
      const int gc = nb0 + wn + nt * 16 + nl;
      const float bv = bias[gc];
#pragma unroll
      for (int mt = 0; mt < 2; mt++)
#pragma unroll
        for (int r = 0; r < 4; r++) {
          const int m = ml0 + wm + mt * 16 + q * 4 + r;
          const float v = acc[mt][nt][r] + bv;
          if (OUT_MODE == 0) {
            out[(((size_t)b * NHEAD + (gc >> 4)) * LTOT + m) * DHD + (gc & 15)] = v;
          } else {
            out[((size_t)b * LTOT + m) * N + gc] = v;
          }
        }
    }
  }
}

// Halo-LDS sampler. Block = one (b, h, 8x8 l-tile); 256 thr = 64 l x 4 point-pairs.
// Offsets are clamped to +-10 px -> halo = 29x29 pixels x 64 B = 53.8 KB LDS.
__global__ __launch_bounds__(256) void sampler(const float* __restrict__ value,
                                               const float* __restrict__ offraw,
                                               const float* __restrict__ attnraw,
                                               float* __restrict__ attout) {
  __shared__ float SH[29 * 29 * 16];
  const int t = threadIdx.x;
  const int h = blockIdx.y;
  const int b = blockIdx.z;
  const int x0 = (blockIdx.x & 7) * 8;
  const int y0 = (blockIdx.x >> 3) * 8;
  const int hx0 = x0 - 10, hy0 = y0 - 10;

  // ---- stage halo (border-replicated) ----
  const float* vb = value + ((size_t)b * NHEAD + h) * (LTOT * DHD);
  for (int idx = t; idx < 29 * 29 * 4; idx += 256) {
    const int hp = idx >> 2, qc = idx & 3;
    const int hy = hp / 29;
    const int hx = hp - hy * 29;
    const int gy = min(max(hy0 + hy, 0), HS - 1);
    const int gx = min(max(hx0 + hx, 0), WS - 1);
    const float4 v = *(const float4*)(vb + (size_t)((gy << 6) + gx) * DHD + qc * 4);
    *(float4*)(SH + hp * 16 + qc * 4) = v;
  }
  __syncthreads();

  // ---- sample: thread = (li, pq); li -> l in tile, pq -> 2 points ----
  const int li = t >> 2;
  const int pq = t & 3;
  const int lx = li & 7, ly = li >> 3;
  const int gxq = x0 + lx, gyq = y0 + ly;
  const int l = (gyq << 6) + gxq;
  const size_t bl = (size_t)b * LTOT + l;

  const float4 off4 = *(const float4*)(offraw + bl * 128 + h * 16 + pq * 4);
  const float2 lg2 = *(const float2*)(attnraw + bl * 64 + h * 8 + pq * 2);

  // softmax over 8 points (4 lanes x 2)
  float m = fmaxf(lg2.x, lg2.y);
  m = fmaxf(m, __shfl_xor(m, 1));
  m = fmaxf(m, __shfl_xor(m, 2));
  const float e0 = __expf(lg2.x - m);
  const float e1 = __expf(lg2.y - m);
  float s = e0 + e1;
  s += __shfl_xor(s, 1);
  s += __shfl_xor(s, 2);
  const float inv = 1.0f / s;

  float o[16];
#pragma unroll
  for (int d = 0; d < 16; d++) o[d] = 0.0f;

#pragma unroll
  for (int pp = 0; pp < 2; pp++) {
    const float ox = pp ? off4.z : off4.x;
    const float oy = pp ? off4.w : off4.y;
    const float aw = (pp ? e1 : e0) * inv;
    const float px = (float)gxq + 10.0f * fast_tanh(ox);
    const float py = (float)gyq + 10.0f * fast_tanh(oy);
    const float x0f = floorf(px), y0f = floorf(py);
    const float fx = px - x0f, fy = py - y0f;
    const int ix = (int)x0f, iy = (int)y0f;
#pragma unroll
    for (int c = 0; c < 4; c++) {
      const int cdx = c & 1, cdy = c >> 1;
      const int jx = ix + cdx, jy = iy + cdy;
      const float wx = cdx ? fx : 1.0f - fx;
      const float wy = cdy ? fy : 1.0f - fy;
      const bool valid = ((unsigned)jx < WS) & ((unsigned)jy < HS);
      const float wc = valid ? aw * wx * wy : 0.0f;
      const int hx = min(max(jx, 0), WS - 1) - hx0;
      const int hy = min(max(jy, 0), HS - 1) - hy0;
      const float* pb = SH + (hy * 29 + hx) * 16;
#pragma unroll
      for (int sC = 0; sC < 4; sC++) {
        const int phys = (sC + li) & 3;  // rotate chunk per-thread: spreads LDS bank groups
        const float4 v = *(const float4*)(pb + phys * 4);
        o[phys * 4 + 0] += wc * v.x;
        o[phys * 4 + 1] += wc * v.y;
        o[phys * 4 + 2] += wc * v.z;
        o[phys * 4 + 3] += wc * v.w;
      }
    }
  }

  // reduce over the 4 point-pair lanes
#pragma unroll
  for (int d = 0; d < 16; d++) {
    o[d] += __shfl_xor(o[d], 1);
    o[d] += __shfl_xor(o[d], 2);
  }

  // lane pq stores channel chunk pq -> row-major attout [b][l][128]
  float4 st = {o[pq * 4 + 0], o[pq * 4 + 1], o[pq * 4 + 2], o[pq * 4 + 3]};
  *(float4*)(attout + bl * 128 + h * 16 + pq * 4) = st;
}

extern "C" void kernel_launch(void* const* d_in, const int* in_sizes, int n_in,
                              void* d_out, int out_size, void* d_ws, size_t ws_size,
                              hipStream_t stream) {
  const float* nbr    = (const float*)d_in[0];
  const float* ext    = (const float*)d_in[1];
  const float* W_val  = (const float*)d_in[2];
  const float* b_val  = (const float*)d_in[3];
  const float* W_off  = (const float*)d_in[4];
  const float* b_off  = (const float*)d_in[5];
  const float* W_attn = (const float*)d_in[6];
  const float* b_attn = (const float*)d_in[7];
  const float* W_out  = (const float*)d_in[8];
  const float* b_out  = (const float*)d_in[9];
  float* out = (float*)d_out;

  float* value   = (float*)d_ws;                                // 16 MB [b][h][l][16]
  float* offraw  = value + (size_t)HB * NHEAD * LTOT * DHD;     // 16 MB [b][l][128]
  float* attnraw = offraw + (size_t)HB * LTOT * CM;             // 8 MB  [b][l][64]
  float* attout  = attnraw + (size_t)HB * LTOT * 64;            // 16 MB [b][l][128]

  dim3 blk(256);
  gemm_mfma<128, 0, 0><<<dim3(64, 2, HB), blk, 0, stream>>>(nbr, W_val, b_val, value);
  gemm_mfma<128, 0, 1><<<dim3(64, 2, HB), blk, 0, stream>>>(ext, W_off, b_off, offraw);
  gemm_mfma<64, 0, 1><<<dim3(64, 1, HB), blk, 0, stream>>>(ext, W_attn, b_attn, attnraw);
  sampler<<<dim3(64, NHEAD, HB), blk, 0, stream>>>(value, offraw, attnraw, attout);
  gemm_mfma<128, 1, 2><<<dim3(64, 2, HB), blk, 0, stream>>>(attout, W_out, b_out, out);
}

// Round 5
// 157.342 us; speedup vs baseline: 2.4221x; 2.4221x over previous
//
#include <hip/hip_runtime.h>
#include <cstdint>

#define HB 8
#define CM 128
#define NHEAD 8
#define NPT 8
#define DHD 16
#define HS 64
#define WS 64
#define LTOT 4096
#define NQA 192   // fused off(128) + attn(64)

typedef float floatx4 __attribute__((ext_vector_type(4)));
typedef short bf16x8 __attribute__((ext_vector_type(8)));

__device__ __forceinline__ unsigned short f2bf_rne(float x) {
  unsigned u = __float_as_uint(x);
  return (unsigned short)((u + 0x7FFFu + ((u >> 16) & 1)) >> 16);
}
// truncation split: x ~= hi + lo, |residual| <= 2^-16 |x|
__device__ __forceinline__ void split_bf(float x, unsigned short& h, unsigned short& l) {
  unsigned u = __float_as_uint(x);
  h = (unsigned short)(u >> 16);
  float r = x - __uint_as_float(u & 0xFFFF0000u);
  l = (unsigned short)(__float_as_uint(r) >> 16);
}
__device__ __forceinline__ float fast_tanh(float x) {
  float e = __expf(2.0f * x);
  return 1.0f - 2.0f / (e + 1.0f);
}

// Convert the 4 weight matrices to bf16 hi/lo fragment layout, once per call.
// Fragment layout per matrix (plane = Nn*128 ushorts, lo plane after hi):
//   element (n, k) at (k>>3)*Nn*8 + n*8 + (k&7)
// wf_qa holds W_off cols as n=0..127 and W_attn as n=128..191 (Nn=192).
// Also fuses bias_off|bias_attn into bias_qa[192].
__global__ __launch_bounds__(256) void prep(const float* __restrict__ Wv,
                                            const float* __restrict__ Wo,
                                            const float* __restrict__ Wa,
                                            const float* __restrict__ Ww,
                                            const float* __restrict__ bo,
                                            const float* __restrict__ ba,
                                            unsigned short* __restrict__ wf_val,
                                            unsigned short* __restrict__ wf_qa,
                                            unsigned short* __restrict__ wf_out,
                                            float* __restrict__ bias_qa) {
  const int gid = blockIdx.x * 256 + threadIdx.x;  // 14336 = 32 k4 * 448 n
  const int k4 = gid / 448;
  const int ng = gid - k4 * 448;

  const float* src;
  unsigned short* dst;
  int Nsrc, Nn, nd, n;
  if (ng < 128) {        src = Wv; dst = wf_val; Nsrc = 128; Nn = 128; n = ng;        nd = n; }
  else if (ng < 256) {   src = Wo; dst = wf_qa;  Nsrc = 128; Nn = 192; n = ng - 128;  nd = n; }
  else if (ng < 320) {   src = Wa; dst = wf_qa;  Nsrc = 64;  Nn = 192; n = ng - 256;  nd = n + 128; }
  else {                 src = Ww; dst = wf_out; Nsrc = 128; Nn = 128; n = ng - 320;  nd = n; }

  ushort4 hi, lo;
  split_bf(src[(k4 * 4 + 0) * Nsrc + n], hi.x, lo.x);
  split_bf(src[(k4 * 4 + 1) * Nsrc + n], hi.y, lo.y);
  split_bf(src[(k4 * 4 + 2) * Nsrc + n], hi.z, lo.z);
  split_bf(src[(k4 * 4 + 3) * Nsrc + n], hi.w, lo.w);
  const int off = (k4 >> 1) * Nn * 8 + nd * 8 + (k4 & 1) * 4;
  *(ushort4*)(dst + off) = hi;
  *(ushort4*)(dst + Nn * 128 + off) = lo;

  if (gid < 128) bias_qa[gid] = bo[gid];
  else if (gid < 192) bias_qa[gid] = ba[gid - 128];
}

// MFMA GEMM, tile 64m x 64n, 4 waves (each 32m x 32n), K=128.
// W fragments preloaded from prepped global buffers (L2-hot) into VGPRs.
// AMODE 0: A fp32 [b][128 k][LTOT l]; 3-term bf16 split (Al*Bh + Ah*Bl + Ah*Bh).
// AMODE 2: A bf16 [b][LTOT l][128 k] (ushort); 2-term (Ah*Bl + Ah*Bh).
// OUT 0: value layout out[((b*8 + n/16)*LTOT + m)*16 + n%16]
// OUT 1: row-major    out[(b*LTOT + m)*N + n]
// OUT 2: bchw         out[(b*CM + n)*LTOT + m] via LDS-transpose epilogue
template <int N, int AMODE, int OUT_MODE>
__global__ __launch_bounds__(256, 4) void gemm_mfma(const void* __restrict__ Av,
                                                    const unsigned short* __restrict__ WF,
                                                    const float* __restrict__ bias,
                                                    float* __restrict__ out) {
  __shared__ char smem[32768];
  unsigned short* AB = (unsigned short*)smem;  // hi [64][128]; lo at +8192 (AMODE 0)
  const int t = threadIdx.x;
  const int ml0 = blockIdx.x * 64;
  const int nb0 = blockIdx.y * 64;
  const int b = blockIdx.z;
  const int w = t >> 6, lane = t & 63;
  const int wm = (w >> 1) * 32, wn = (w & 1) * 32;
  const int nl = lane & 15, q = lane >> 4;

  // ---- preload W fragments (independent of LDS; latency overlaps A staging) ----
  bf16x8 wh[2][4], wl[2][4];
#pragma unroll
  for (int nt = 0; nt < 2; nt++) {
    const int n = nb0 + wn + nt * 16 + nl;
#pragma unroll
    for (int K0 = 0; K0 < 4; K0++) {
      const size_t o = (size_t)(K0 * 4 + q) * N * 8 + n * 8;
      wh[nt][K0] = *(const bf16x8*)(WF + o);
      wl[nt][K0] = *(const bf16x8*)(WF + (size_t)N * 128 + o);
    }
  }

  // ---- stage A into LDS (swizzle: (x,k) -> x*128 + ((k>>3)^(x&15))*8 + (k&7)) ----
  if (AMODE == 0) {
    const float* src = (const float*)Av + (size_t)b * CM * LTOT + ml0;
    const int x = t & 63, kq = t >> 6;
#pragma unroll
    for (int i = 0; i < 8; i++) {
      const int kb = kq * 4 + i * 16;
      ushort4 hi, lo;
      split_bf(src[(size_t)(kb + 0) * LTOT + x], hi.x, lo.x);
      split_bf(src[(size_t)(kb + 1) * LTOT + x], hi.y, lo.y);
      split_bf(src[(size_t)(kb + 2) * LTOT + x], hi.z, lo.z);
      split_bf(src[(size_t)(kb + 3) * LTOT + x], hi.w, lo.w);
      const int off = x * 128 + (((kb >> 3) ^ (x & 15)) << 3) + (kb & 7);
      *(ushort4*)(AB + off) = hi;
      *(ushort4*)(AB + 8192 + off) = lo;
    }
  } else {
    const unsigned short* src = (const unsigned short*)Av + ((size_t)b * LTOT + ml0) * CM;
#pragma unroll
    for (int i = 0; i < 4; i++) {
      const int idx = t + i * 256;     // 1024 chunks of 8 bf16
      const int x = idx >> 4, kc = idx & 15;
      const uint4 v = *(const uint4*)(src + (size_t)x * CM + kc * 8);
      *(uint4*)(AB + x * 128 + ((kc ^ (x & 15)) << 3)) = v;
    }
  }
  __syncthreads();

  // ---- K loop ----
  floatx4 acc[2][2];
#pragma unroll
  for (int mt = 0; mt < 2; mt++)
#pragma unroll
    for (int nt = 0; nt < 2; nt++) acc[mt][nt] = {0.0f, 0.0f, 0.0f, 0.0f};

#pragma unroll
  for (int K0 = 0; K0 < 4; K0++) {
    bf16x8 ah[2], al[2];
#pragma unroll
    for (int mt = 0; mt < 2; mt++) {
      const int m = wm + mt * 16 + nl;
      const int off = m * 128 + (((K0 * 4 + q) ^ (m & 15)) << 3);
      ah[mt] = *(bf16x8*)(AB + off);
      if (AMODE == 0) al[mt] = *(bf16x8*)(AB + 8192 + off);
    }
#pragma unroll
    for (int mt = 0; mt < 2; mt++)
#pragma unroll
      for (int nt = 0; nt < 2; nt++) {
        if (AMODE == 0)
          acc[mt][nt] = __builtin_amdgcn_mfma_f32_16x16x32_bf16(al[mt], wh[nt][K0], acc[mt][nt], 0, 0, 0);
        acc[mt][nt] = __builtin_amdgcn_mfma_f32_16x16x32_bf16(ah[mt], wl[nt][K0], acc[mt][nt], 0, 0, 0);
        acc[mt][nt] = __builtin_amdgcn_mfma_f32_16x16x32_bf16(ah[mt], wh[nt][K0], acc[mt][nt], 0, 0, 0);
      }
  }

  // ---- epilogue (C/D: col=lane&15, row=q*4+reg — m91-verified) ----
  if (OUT_MODE == 2) {
    __syncthreads();
    float* LF = (float*)smem;  // [64 n][65]
#pragma unroll
    for (int mt = 0; mt < 2; mt++)
#pragma unroll
      for (int nt = 0; nt < 2; nt++) {
        const int n = wn + nt * 16 + nl;
#pragma unroll
        for (int r = 0; r < 4; r++) LF[n * 65 + wm + mt * 16 + q * 4 + r] = acc[mt][nt][r];
      }
    __syncthreads();
#pragma unroll
    for (int i = 0; i < 16; i++) {
      const int idx = t + i * 256;
      const int n = idx >> 6, m = idx & 63;
      out[((size_t)b * CM + nb0 + n) * LTOT + ml0 + m] = LF[n * 65 + m] + bias[nb0 + n];
    }
  } else {
#pragma unroll
    for (int nt = 0; nt < 2; nt++) {
      const int gc = nb0 + wn + nt * 16 + nl;
      const float bv = bias[gc];
#pragma unroll
      for (int mt = 0; mt < 2; mt++)
#pragma unroll
        for (int r = 0; r < 4; r++) {
          const int m = ml0 + wm + mt * 16 + q * 4 + r;
          const float v = acc[mt][nt][r] + bv;
          if (OUT_MODE == 0)
            out[(((size_t)b * NHEAD + (gc >> 4)) * LTOT + m) * DHD + (gc & 15)] = v;
          else
            out[((size_t)b * LTOT + m) * N + gc] = v;
        }
    }
  }
}

// Quad-cooperative sampler. lane = d4(2b) | p(3b) | li(1b); 4 d4-lanes share each
// 64 B pixel line (16 lines per load instr vs 64 naive). No LDS. Block covers
// 8 l for one (b,h). Writes attout as bf16 [b][l][128].
__global__ __launch_bounds__(256) void sampler(const float* __restrict__ value,
                                               const float* __restrict__ qa,
                                               unsigned short* __restrict__ attout) {
  const int t = threadIdx.x;
  const int lane = t & 63;
  const int w = t >> 6;
  const int d4 = lane & 3;
  const int p = (lane >> 2) & 7;
  const int li = lane >> 5;
  const int h = blockIdx.y;
  const int b = blockIdx.z;
  const int l = blockIdx.x * 8 + w * 2 + li;
  const size_t bl = (size_t)b * LTOT + l;

  const float2 off2 = *(const float2*)(qa + bl * NQA + h * 16 + p * 2);
  const float logit = qa[bl * NQA + 128 + h * 8 + p];

  // softmax over the 8 p-lanes
  float m = logit;
  m = fmaxf(m, __shfl_xor(m, 4));
  m = fmaxf(m, __shfl_xor(m, 8));
  m = fmaxf(m, __shfl_xor(m, 16));
  const float e = __expf(logit - m);
  float s = e;
  s += __shfl_xor(s, 4);
  s += __shfl_xor(s, 8);
  s += __shfl_xor(s, 16);
  const float aw = e / s;

  const float px = (float)(l & (WS - 1)) + 10.0f * fast_tanh(off2.x);
  const float py = (float)(l >> 6) + 10.0f * fast_tanh(off2.y);
  const float x0f = floorf(px), y0f = floorf(py);
  const float fx = px - x0f, fy = py - y0f;
  const int ix = (int)x0f, iy = (int)y0f;

  const float* vb = value + ((size_t)b * NHEAD + h) * (LTOT * DHD) + d4 * 4;
  float4 o = {0.0f, 0.0f, 0.0f, 0.0f};
#pragma unroll
  for (int c = 0; c < 4; c++) {
    const int cdx = c & 1, cdy = c >> 1;
    const int jx = ix + cdx, jy = iy + cdy;
    const float wx = cdx ? fx : 1.0f - fx;
    const float wy = cdy ? fy : 1.0f - fy;
    const bool valid = ((unsigned)jx < WS) & ((unsigned)jy < HS);
    const float wc = valid ? aw * wx * wy : 0.0f;
    const int cx = min(max(jx, 0), WS - 1);
    const int cy = min(max(jy, 0), HS - 1);
    const float4 v = *(const float4*)(vb + (size_t)((cy << 6) + cx) * DHD);
    o.x += wc * v.x;
    o.y += wc * v.y;
    o.z += wc * v.z;
    o.w += wc * v.w;
  }

  // reduce over the 8 points (p-lanes)
  o.x += __shfl_xor(o.x, 4);  o.y += __shfl_xor(o.y, 4);
  o.z += __shfl_xor(o.z, 4);  o.w += __shfl_xor(o.w, 4);
  o.x += __shfl_xor(o.x, 8);  o.y += __shfl_xor(o.y, 8);
  o.z += __shfl_xor(o.z, 8);  o.w += __shfl_xor(o.w, 8);
  o.x += __shfl_xor(o.x, 16); o.y += __shfl_xor(o.y, 16);
  o.z += __shfl_xor(o.z, 16); o.w += __shfl_xor(o.w, 16);

  if (p == 0) {
    ushort4 st = {f2bf_rne(o.x), f2bf_rne(o.y), f2bf_rne(o.z), f2bf_rne(o.w)};
    *(ushort4*)(attout + bl * CM + h * 16 + d4 * 4) = st;
  }
}

extern "C" void kernel_launch(void* const* d_in, const int* in_sizes, int n_in,
                              void* d_out, int out_size, void* d_ws, size_t ws_size,
                              hipStream_t stream) {
  const float* nbr    = (const float*)d_in[0];
  const float* ext    = (const float*)d_in[1];
  const float* W_val  = (const float*)d_in[2];
  const float* b_val  = (const float*)d_in[3];
  const float* W_off  = (const float*)d_in[4];
  const float* b_off  = (const float*)d_in[5];
  const float* W_attn = (const float*)d_in[6];
  const float* b_attn = (const float*)d_in[7];
  const float* W_out  = (const float*)d_in[8];
  const float* b_out  = (const float*)d_in[9];
  float* out = (float*)d_out;

  float* value = (float*)d_ws;                               // 16.78 MB [b][h][l][16]
  float* qa    = value + (size_t)HB * NHEAD * LTOT * DHD;    // 25.17 MB [b][l][192]
  unsigned short* attbf = (unsigned short*)(qa + (size_t)HB * LTOT * NQA);  // 8.39 MB bf16 [b][l][128]
  unsigned short* wf_val = attbf + (size_t)HB * LTOT * CM;   // 64 KB
  unsigned short* wf_qa  = wf_val + 128 * 128 * 2;           // 96 KB
  unsigned short* wf_out = wf_qa + 192 * 128 * 2;            // 64 KB
  float* bias_qa = (float*)(wf_out + 128 * 128 * 2);         // 768 B

  prep<<<56, 256, 0, stream>>>(W_val, W_off, W_attn, W_out, b_off, b_attn,
                               wf_val, wf_qa, wf_out, bias_qa);
  gemm_mfma<128, 0, 0><<<dim3(64, 2, HB), 256, 0, stream>>>(nbr, wf_val, b_val, value);
  gemm_mfma<192, 0, 1><<<dim3(64, 3, HB), 256, 0, stream>>>(ext, wf_qa, bias_qa, qa);
  sampler<<<dim3(LTOT / 8, NHEAD, HB), 256, 0, stream>>>(value, qa, attbf);
  gemm_mfma<128, 2, 2><<<dim3(64, 2, HB), 256, 0, stream>>>(attbf, wf_out, b_out, out);
}

// Round 6
// 148.609 us; speedup vs baseline: 2.5645x; 1.0588x over previous
//
#include <hip/hip_runtime.h>
#include <cstdint>

#define HB 8
#define CM 128
#define NHEAD 8
#define NPT 8
#define DHD 16
#define HS 64
#define WS 64
#define LTOT 4096
#define NQA 192   // fused off(128) + attn(64)

typedef float floatx4 __attribute__((ext_vector_type(4)));
typedef short bf16x8 __attribute__((ext_vector_type(8)));

__device__ __forceinline__ unsigned short f2bf_rne(float x) {
  unsigned u = __float_as_uint(x);
  return (unsigned short)((u + 0x7FFFu + ((u >> 16) & 1)) >> 16);
}
// truncation split: x ~= hi + lo, |residual| <= 2^-16 |x|
__device__ __forceinline__ void split_bf(float x, unsigned short& h, unsigned short& l) {
  unsigned u = __float_as_uint(x);
  h = (unsigned short)(u >> 16);
  float r = x - __uint_as_float(u & 0xFFFF0000u);
  l = (unsigned short)(__float_as_uint(r) >> 16);
}
__device__ __forceinline__ float fast_tanh(float x) {
  float e = __expf(2.0f * x);
  return 1.0f - 2.0f / (e + 1.0f);
}

// Convert the 4 weight matrices to bf16 hi/lo fragment layout, once per call.
// Fragment layout per matrix (plane = Nn*128 ushorts, lo plane after hi):
//   element (n, k) at (k>>3)*Nn*8 + n*8 + (k&7)
__global__ __launch_bounds__(256) void prep(const float* __restrict__ Wv,
                                            const float* __restrict__ Wo,
                                            const float* __restrict__ Wa,
                                            const float* __restrict__ Ww,
                                            const float* __restrict__ bo,
                                            const float* __restrict__ ba,
                                            unsigned short* __restrict__ wf_val,
                                            unsigned short* __restrict__ wf_qa,
                                            unsigned short* __restrict__ wf_out,
                                            float* __restrict__ bias_qa) {
  const int gid = blockIdx.x * 256 + threadIdx.x;  // 14336 = 32 k4 * 448 n
  const int k4 = gid / 448;
  const int ng = gid - k4 * 448;

  const float* src;
  unsigned short* dst;
  int Nsrc, Nn, nd, n;
  if (ng < 128) {        src = Wv; dst = wf_val; Nsrc = 128; Nn = 128; n = ng;        nd = n; }
  else if (ng < 256) {   src = Wo; dst = wf_qa;  Nsrc = 128; Nn = 192; n = ng - 128;  nd = n; }
  else if (ng < 320) {   src = Wa; dst = wf_qa;  Nsrc = 64;  Nn = 192; n = ng - 256;  nd = n + 128; }
  else {                 src = Ww; dst = wf_out; Nsrc = 128; Nn = 128; n = ng - 320;  nd = n; }

  ushort4 hi, lo;
  split_bf(src[(k4 * 4 + 0) * Nsrc + n], hi.x, lo.x);
  split_bf(src[(k4 * 4 + 1) * Nsrc + n], hi.y, lo.y);
  split_bf(src[(k4 * 4 + 2) * Nsrc + n], hi.z, lo.z);
  split_bf(src[(k4 * 4 + 3) * Nsrc + n], hi.w, lo.w);
  const int off = (k4 >> 1) * Nn * 8 + nd * 8 + (k4 & 1) * 4;
  *(ushort4*)(dst + off) = hi;
  *(ushort4*)(dst + Nn * 128 + off) = lo;

  if (gid < 128) bias_qa[gid] = bo[gid];
  else if (gid < 192) bias_qa[gid] = ba[gid - 128];
}

// MFMA GEMM body, tile 64m x 64n, 4 waves (each 32m x 32n), K=128.
// W fragments streamed from prepped global buffers (L2-hot) INSIDE the K-loop
// (compiler hoists as register budget allows — no forced 64-reg preload).
// AMODE 0: A fp32 [b][128 k][LTOT l]; 3-term bf16 split.
// AMODE 2: A bf16 [b][LTOT l][128 k] (ushort); 2-term.
// OUT 0: value layout; OUT 1: row-major [b][l][N]; OUT 2: bchw via LDS transpose.
template <int N, int AMODE, int OUT_MODE>
__device__ __forceinline__ void gemm_body(const void* __restrict__ Av,
                                          const unsigned short* __restrict__ WF,
                                          const float* __restrict__ bias,
                                          float* __restrict__ out,
                                          int b, int ml0, int nb0, int t, char* smem) {
  unsigned short* AB = (unsigned short*)smem;  // hi [64][128]; lo at +8192 (AMODE 0)
  const int w = t >> 6, lane = t & 63;
  const int wm = (w >> 1) * 32, wn = (w & 1) * 32;
  const int nl = lane & 15, q = lane >> 4;

  // ---- stage A into LDS (swizzle: (x,k) -> x*128 + ((k>>3)^(x&15))*8 + (k&7)) ----
  if (AMODE == 0) {
    const float* src = (const float*)Av + (size_t)b * CM * LTOT + ml0;
    const int x = t & 63, kq = t >> 6;
#pragma unroll
    for (int i = 0; i < 8; i++) {
      const int kb = kq * 4 + i * 16;
      ushort4 hi, lo;
      split_bf(src[(size_t)(kb + 0) * LTOT + x], hi.x, lo.x);
      split_bf(src[(size_t)(kb + 1) * LTOT + x], hi.y, lo.y);
      split_bf(src[(size_t)(kb + 2) * LTOT + x], hi.z, lo.z);
      split_bf(src[(size_t)(kb + 3) * LTOT + x], hi.w, lo.w);
      const int off = x * 128 + (((kb >> 3) ^ (x & 15)) << 3) + (kb & 7);
      *(ushort4*)(AB + off) = hi;
      *(ushort4*)(AB + 8192 + off) = lo;
    }
  } else {
    const unsigned short* src = (const unsigned short*)Av + ((size_t)b * LTOT + ml0) * CM;
#pragma unroll
    for (int i = 0; i < 4; i++) {
      const int idx = t + i * 256;     // 1024 chunks of 8 bf16
      const int x = idx >> 4, kc = idx & 15;
      const uint4 v = *(const uint4*)(src + (size_t)x * CM + kc * 8);
      *(uint4*)(AB + x * 128 + ((kc ^ (x & 15)) << 3)) = v;
    }
  }
  __syncthreads();

  // ---- K loop ----
  floatx4 acc[2][2];
#pragma unroll
  for (int mt = 0; mt < 2; mt++)
#pragma unroll
    for (int nt = 0; nt < 2; nt++) acc[mt][nt] = {0.0f, 0.0f, 0.0f, 0.0f};

#pragma unroll
  for (int K0 = 0; K0 < 4; K0++) {
    bf16x8 ah[2], al[2];
#pragma unroll
    for (int mt = 0; mt < 2; mt++) {
      const int m = wm + mt * 16 + nl;
      const int off = m * 128 + (((K0 * 4 + q) ^ (m & 15)) << 3);
      ah[mt] = *(bf16x8*)(AB + off);
      if (AMODE == 0) al[mt] = *(bf16x8*)(AB + 8192 + off);
    }
    bf16x8 wh[2], wl[2];
#pragma unroll
    for (int nt = 0; nt < 2; nt++) {
      const int n = nb0 + wn + nt * 16 + nl;
      const size_t o = (size_t)(K0 * 4 + q) * N * 8 + n * 8;
      wh[nt] = *(const bf16x8*)(WF + o);
      wl[nt] = *(const bf16x8*)(WF + (size_t)N * 128 + o);
    }
#pragma unroll
    for (int mt = 0; mt < 2; mt++)
#pragma unroll
      for (int nt = 0; nt < 2; nt++) {
        if (AMODE == 0)
          acc[mt][nt] = __builtin_amdgcn_mfma_f32_16x16x32_bf16(al[mt], wh[nt], acc[mt][nt], 0, 0, 0);
        acc[mt][nt] = __builtin_amdgcn_mfma_f32_16x16x32_bf16(ah[mt], wl[nt], acc[mt][nt], 0, 0, 0);
        acc[mt][nt] = __builtin_amdgcn_mfma_f32_16x16x32_bf16(ah[mt], wh[nt], acc[mt][nt], 0, 0, 0);
      }
  }

  // ---- epilogue (C/D: col=lane&15, row=q*4+reg — m91-verified) ----
  if (OUT_MODE == 2) {
    __syncthreads();
    float* LF = (float*)smem;  // [64 n][65]
#pragma unroll
    for (int mt = 0; mt < 2; mt++)
#pragma unroll
      for (int nt = 0; nt < 2; nt++) {
        const int n = wn + nt * 16 + nl;
#pragma unroll
        for (int r = 0; r < 4; r++) LF[n * 65 + wm + mt * 16 + q * 4 + r] = acc[mt][nt][r];
      }
    __syncthreads();
#pragma unroll
    for (int i = 0; i < 16; i++) {
      const int idx = t + i * 256;
      const int n = idx >> 6, m = idx & 63;
      out[((size_t)b * CM + nb0 + n) * LTOT + ml0 + m] = LF[n * 65 + m] + bias[nb0 + n];
    }
  } else {
#pragma unroll
    for (int nt = 0; nt < 2; nt++) {
      const int gc = nb0 + wn + nt * 16 + nl;
      const float bv = bias[gc];
#pragma unroll
      for (int mt = 0; mt < 2; mt++)
#pragma unroll
        for (int r = 0; r < 4; r++) {
          const int m = ml0 + wm + mt * 16 + q * 4 + r;
          const float v = acc[mt][nt][r] + bv;
          if (OUT_MODE == 0)
            out[(((size_t)b * NHEAD + (gc >> 4)) * LTOT + m) * DHD + (gc & 15)] = v;
          else
            out[((size_t)b * LTOT + m) * N + gc] = v;
        }
    }
  }
}

// Fused value-GEMM (y<2) + qa-GEMM (y>=2): block-uniform branch.
__global__ __launch_bounds__(256, 4) void gemm_vq(const float* __restrict__ nbr,
                                                  const float* __restrict__ ext,
                                                  const unsigned short* __restrict__ wf_val,
                                                  const unsigned short* __restrict__ wf_qa,
                                                  const float* __restrict__ b_val,
                                                  const float* __restrict__ bias_qa,
                                                  float* __restrict__ value,
                                                  float* __restrict__ qa) {
  __shared__ char smem[32768];
  const int b = blockIdx.z, ml0 = blockIdx.x * 64;
  if (blockIdx.y < 2)
    gemm_body<128, 0, 0>(nbr, wf_val, b_val, value, b, ml0, blockIdx.y * 64, threadIdx.x, smem);
  else
    gemm_body<192, 0, 1>(ext, wf_qa, bias_qa, qa, b, ml0, (blockIdx.y - 2) * 64, threadIdx.x, smem);
}

__global__ __launch_bounds__(256, 4) void gemm_outk(const unsigned short* __restrict__ attbf,
                                                    const unsigned short* __restrict__ wf_out,
                                                    const float* __restrict__ b_out,
                                                    float* __restrict__ out) {
  __shared__ char smem[32768];
  gemm_body<128, 2, 2>(attbf, wf_out, b_out, out, blockIdx.z, blockIdx.x * 64,
                       blockIdx.y * 64, threadIdx.x, smem);
}

// Quad-cooperative sampler, 4 l-iterations per wave.
// lane = d4(2b) | p(3b) | li(1b); 4 d4-lanes share each 64 B pixel line.
// qa operands for all 4 iterations preloaded (independent loads -> ILP).
__global__ __launch_bounds__(256) void sampler(const float* __restrict__ value,
                                               const float* __restrict__ qa,
                                               unsigned short* __restrict__ attout) {
  const int t = threadIdx.x;
  const int lane = t & 63;
  const int w = t >> 6;
  const int d4 = lane & 3;
  const int p = (lane >> 2) & 7;
  const int li = lane >> 5;
  const int h = blockIdx.y;
  const int b = blockIdx.z;
  const int l0 = blockIdx.x * 32 + w * 8;  // wave covers l0..l0+7

  float2 off2[4];
  float lg[4];
#pragma unroll
  for (int it = 0; it < 4; it++) {
    const size_t bl = (size_t)b * LTOT + l0 + it * 2 + li;
    off2[it] = *(const float2*)(qa + bl * NQA + h * 16 + p * 2);
    lg[it] = qa[bl * NQA + 128 + h * 8 + p];
  }

  const float* vb = value + ((size_t)b * NHEAD + h) * (LTOT * DHD) + d4 * 4;

#pragma unroll
  for (int it = 0; it < 4; it++) {
    const int l = l0 + it * 2 + li;
    const size_t bl = (size_t)b * LTOT + l;

    // softmax over the 8 p-lanes
    float m = lg[it];
    m = fmaxf(m, __shfl_xor(m, 4));
    m = fmaxf(m, __shfl_xor(m, 8));
    m = fmaxf(m, __shfl_xor(m, 16));
    const float e = __expf(lg[it] - m);
    float s = e;
    s += __shfl_xor(s, 4);
    s += __shfl_xor(s, 8);
    s += __shfl_xor(s, 16);
    const float aw = e / s;

    const float px = (float)(l & (WS - 1)) + 10.0f * fast_tanh(off2[it].x);
    const float py = (float)(l >> 6) + 10.0f * fast_tanh(off2[it].y);
    const float x0f = floorf(px), y0f = floorf(py);
    const float fx = px - x0f, fy = py - y0f;
    const int ix = (int)x0f, iy = (int)y0f;

    float4 o = {0.0f, 0.0f, 0.0f, 0.0f};
#pragma unroll
    for (int c = 0; c < 4; c++) {
      const int cdx = c & 1, cdy = c >> 1;
      const int jx = ix + cdx, jy = iy + cdy;
      const float wx = cdx ? fx : 1.0f - fx;
      const float wy = cdy ? fy : 1.0f - fy;
      const bool valid = ((unsigned)jx < WS) & ((unsigned)jy < HS);
      const float wc = valid ? aw * wx * wy : 0.0f;
      const int cx = min(max(jx, 0), WS - 1);
      const int cy = min(max(jy, 0), HS - 1);
      const float4 v = *(const float4*)(vb + (size_t)((cy << 6) + cx) * DHD);
      o.x += wc * v.x;
      o.y += wc * v.y;
      o.z += wc * v.z;
      o.w += wc * v.w;
    }

    // reduce over the 8 points (p-lanes)
    o.x += __shfl_xor(o.x, 4);  o.y += __shfl_xor(o.y, 4);
    o.z += __shfl_xor(o.z, 4);  o.w += __shfl_xor(o.w, 4);
    o.x += __shfl_xor(o.x, 8);  o.y += __shfl_xor(o.y, 8);
    o.z += __shfl_xor(o.z, 8);  o.w += __shfl_xor(o.w, 8);
    o.x += __shfl_xor(o.x, 16); o.y += __shfl_xor(o.y, 16);
    o.z += __shfl_xor(o.z, 16); o.w += __shfl_xor(o.w, 16);

    if (p == 0) {
      ushort4 st = {f2bf_rne(o.x), f2bf_rne(o.y), f2bf_rne(o.z), f2bf_rne(o.w)};
      *(ushort4*)(attout + bl * CM + h * 16 + d4 * 4) = st;
    }
  }
}

extern "C" void kernel_launch(void* const* d_in, const int* in_sizes, int n_in,
                              void* d_out, int out_size, void* d_ws, size_t ws_size,
                              hipStream_t stream) {
  const float* nbr    = (const float*)d_in[0];
  const float* ext    = (const float*)d_in[1];
  const float* W_val  = (const float*)d_in[2];
  const float* b_val  = (const float*)d_in[3];
  const float* W_off  = (const float*)d_in[4];
  const float* b_off  = (const float*)d_in[5];
  const float* W_attn = (const float*)d_in[6];
  const float* b_attn = (const float*)d_in[7];
  const float* W_out  = (const float*)d_in[8];
  const float* b_out  = (const float*)d_in[9];
  float* out = (float*)d_out;

  float* value = (float*)d_ws;                               // 16.78 MB [b][h][l][16]
  float* qa    = value + (size_t)HB * NHEAD * LTOT * DHD;    // 25.17 MB [b][l][192]
  unsigned short* attbf = (unsigned short*)(qa + (size_t)HB * LTOT * NQA);  // 8.39 MB bf16 [b][l][128]
  unsigned short* wf_val = attbf + (size_t)HB * LTOT * CM;   // 64 KB
  unsigned short* wf_qa  = wf_val + 128 * 128 * 2;           // 96 KB
  unsigned short* wf_out = wf_qa + 192 * 128 * 2;            // 64 KB
  float* bias_qa = (float*)(wf_out + 128 * 128 * 2);         // 768 B

  prep<<<56, 256, 0, stream>>>(W_val, W_off, W_attn, W_out, b_off, b_attn,
                               wf_val, wf_qa, wf_out, bias_qa);
  gemm_vq<<<dim3(64, 5, HB), 256, 0, stream>>>(nbr, ext, wf_val, wf_qa, b_val, bias_qa, value, qa);
  sampler<<<dim3(LTOT / 32, NHEAD, HB), 256, 0, stream>>>(value, qa, attbf);
  gemm_outk<<<dim3(64, 2, HB), 256, 0, stream>>>(attbf, wf_out, b_out, out);
}